// Round 19
// baseline (101.707 us; speedup 1.0000x reference)
//
#include <hip/hip_runtime.h>

#define I_DIM 128
#define H_DIM 64
#define BATCH 8
#define SEQ   4096
#define NBIN  (SEQ/2 + 1)     // 2049
#define NBIN2 (SEQ + 1)       // 4097

// 3-nibble XOR swizzle — proven r13-r18.
#define SZ(a) ((a) ^ (((a) >> 4) & 15) ^ (((a) >> 8) & 15))

// Module-scope device scratch (graph-capture safe, fully rewritten per call).
__device__ float  g_xT[(size_t)BATCH * I_DIM * SEQ];   // 16.8 MB
__device__ float2 g_Hh[I_DIM * NBIN];                  // 2.1 MB
__device__ float2 g_Kf[I_DIM * NBIN2];                 // 4.2 MB
__device__ float  g_Yt[(size_t)BATCH * I_DIM * SEQ];   // 16.8 MB

__device__ inline float2 cmul(float2 a, float2 b) {
    return make_float2(a.x * b.x - a.y * b.y, a.x * b.y + a.y * b.x);
}
__device__ inline float2 cadd(float2 a, float2 b) { return make_float2(a.x + b.x, a.y + b.y); }
__device__ inline float2 csub(float2 a, float2 b) { return make_float2(a.x - b.x, a.y - b.y); }

// DFT8 — proven r4-r18.
__device__ inline void dft8(float2 a[8]) {
    const float C = 0.70710678118654752f;
    float2 s0 = cadd(a[0], a[4]), s1 = cadd(a[1], a[5]);
    float2 s2 = cadd(a[2], a[6]), s3 = cadd(a[3], a[7]);
    float2 d0 = csub(a[0], a[4]), d1 = csub(a[1], a[5]);
    float2 d2 = csub(a[2], a[6]), d3 = csub(a[3], a[7]);
    d1 = make_float2(C * (d1.x + d1.y), C * (d1.y - d1.x));
    d2 = make_float2(d2.y, -d2.x);
    d3 = make_float2(C * (d3.y - d3.x), -C * (d3.x + d3.y));
    {
        float2 p0 = cadd(s0, s2), p1 = cadd(s1, s3);
        float2 m0 = csub(s0, s2), m1 = csub(s1, s3);
        m1 = make_float2(m1.y, -m1.x);
        a[0] = cadd(p0, p1); a[4] = csub(p0, p1);
        a[2] = cadd(m0, m1); a[6] = csub(m0, m1);
    }
    {
        float2 p0 = cadd(d0, d2), p1 = cadd(d1, d3);
        float2 m0 = csub(d0, d2), m1 = csub(d1, d3);
        m1 = make_float2(m1.y, -m1.x);
        a[1] = cadd(p0, p1); a[5] = csub(p0, p1);
        a[3] = cadd(m0, m1); a[7] = csub(m0, m1);
    }
}

// DFT8 of (x0..x3,0,0,0,0) — proven r8-r18.
__device__ inline void dft8hz(float2 x0, float2 x1, float2 x2, float2 x3,
                              float2 b[8]) {
    const float C = 0.70710678118654752f;
    float2 p0 = cadd(x0, x2), p1 = cadd(x1, x3);
    float2 m0 = csub(x0, x2), m1t = csub(x1, x3);
    float2 m1 = make_float2(m1t.y, -m1t.x);
    b[0] = cadd(p0, p1); b[4] = csub(p0, p1);
    b[2] = cadd(m0, m1); b[6] = csub(m0, m1);
    float2 c1 = make_float2(C * (x1.x + x1.y), C * (x1.y - x1.x));
    float2 c2 = make_float2(x2.y, -x2.x);
    float2 c3 = make_float2(C * (x3.y - x3.x), -C * (x3.x + x3.y));
    float2 q0 = cadd(x0, c2), q1 = cadd(c1, c3);
    float2 n0 = csub(x0, c2), n1t = csub(c1, c3);
    float2 n1 = make_float2(n1t.y, -n1t.x);
    b[1] = cadd(q0, q1); b[5] = csub(q0, q1);
    b[3] = cadd(n0, n1); b[7] = csub(n0, n1);
}

// DIT combine — proven r13-r18.
__device__ inline void combine16(const float2 e[8], const float2 o[8],
                                 float2 b[16]) {
    const float C  = 0.70710678118654752f;
    const float C1 = 0.92387953251128674f;
    const float S1 = 0.38268343236508977f;
    float2 t;
    b[0] = cadd(e[0], o[0]);  b[8]  = csub(e[0], o[0]);
    t = cmul(o[1], make_float2( C1, -S1)); b[1] = cadd(e[1], t); b[9]  = csub(e[1], t);
    t = cmul(o[2], make_float2(  C,  -C)); b[2] = cadd(e[2], t); b[10] = csub(e[2], t);
    t = cmul(o[3], make_float2( S1, -C1)); b[3] = cadd(e[3], t); b[11] = csub(e[3], t);
    t = make_float2(o[4].y, -o[4].x);      b[4] = cadd(e[4], t); b[12] = csub(e[4], t);
    t = cmul(o[5], make_float2(-S1, -C1)); b[5] = cadd(e[5], t); b[13] = csub(e[5], t);
    t = cmul(o[6], make_float2( -C,  -C)); b[6] = cadd(e[6], t); b[14] = csub(e[6], t);
    t = cmul(o[7], make_float2(-C1, -S1)); b[7] = cadd(e[7], t); b[15] = csub(e[7], t);
}

// DFT16 — proven r13-r18.
__device__ inline void dft16(float2 a[16]) {
    float2 e[8] = {a[0], a[2], a[4], a[6], a[8], a[10], a[12], a[14]};
    float2 o[8] = {a[1], a[3], a[5], a[7], a[9], a[11], a[13], a[15]};
    dft8(e); dft8(o);
    combine16(e, o, a);
}

// S1-fused twiddle+write — proven r13-r18.
__device__ inline void s1_twiddle_write(float2* __restrict__ lds, int u,
                                        float2 b[16]) {
    float sn, cs;
    __sincosf((float)(-6.283185307179586 / 4096.0) * (float)u, &sn, &cs);
    float2 w1 = make_float2(cs, sn);
    float2 w2 = cmul(w1, w1), w3 = cmul(w2, w1), w4 = cmul(w2, w2);
    float2 w5 = cmul(w3, w2), w6 = cmul(w3, w3), w7 = cmul(w4, w3);
    float2 w8 = cmul(w4, w4);
    const int base = 16 * u;
    lds[SZ(base + 0)]  = b[0];
    lds[SZ(base + 1)]  = cmul(b[1], w1);
    lds[SZ(base + 2)]  = cmul(b[2], w2);
    lds[SZ(base + 3)]  = cmul(b[3], w3);
    lds[SZ(base + 4)]  = cmul(b[4], w4);
    lds[SZ(base + 5)]  = cmul(b[5], w5);
    lds[SZ(base + 6)]  = cmul(b[6], w6);
    lds[SZ(base + 7)]  = cmul(b[7], w7);
    lds[SZ(base + 8)]  = cmul(b[8], w8);
    lds[SZ(base + 9)]  = cmul(cmul(b[9],  w1), w8);
    lds[SZ(base + 10)] = cmul(cmul(b[10], w2), w8);
    lds[SZ(base + 11)] = cmul(cmul(b[11], w3), w8);
    lds[SZ(base + 12)] = cmul(cmul(b[12], w4), w8);
    lds[SZ(base + 13)] = cmul(cmul(b[13], w5), w8);
    lds[SZ(base + 14)] = cmul(cmul(b[14], w6), w8);
    lds[SZ(base + 15)] = cmul(cmul(b[15], w7), w8);
}

// Radix-16 Stockham stage — proven r13-r18.
template <int S>
__device__ inline void stage16(float2* __restrict__ lds, int u) {
    float2 d[16];
#pragma unroll
    for (int j = 0; j < 16; ++j) d[j] = lds[SZ(u + 256 * j)];
    __syncthreads();
    const int q = u & (S - 1);
    dft16(d);
    if constexpr (S < 256) {
        float sn, cs;
        __sincosf((float)(-6.283185307179586 / 4096.0) * (float)(u - q), &sn, &cs);
        float2 w1 = make_float2(cs, sn);
        float2 w2 = cmul(w1, w1), w3 = cmul(w2, w1), w4 = cmul(w2, w2);
        float2 w5 = cmul(w3, w2), w6 = cmul(w3, w3), w7 = cmul(w4, w3);
        float2 w8 = cmul(w4, w4);
        d[1]  = cmul(d[1], w1);  d[2]  = cmul(d[2], w2);
        d[3]  = cmul(d[3], w3);  d[4]  = cmul(d[4], w4);
        d[5]  = cmul(d[5], w5);  d[6]  = cmul(d[6], w6);
        d[7]  = cmul(d[7], w7);  d[8]  = cmul(d[8], w8);
        d[9]  = cmul(cmul(d[9],  w1), w8);
        d[10] = cmul(cmul(d[10], w2), w8);
        d[11] = cmul(cmul(d[11], w3), w8);
        d[12] = cmul(cmul(d[12], w4), w8);
        d[13] = cmul(cmul(d[13], w5), w8);
        d[14] = cmul(cmul(d[14], w6), w8);
        d[15] = cmul(cmul(d[15], w7), w8);
    }
    const int base = 16 * u - 15 * q;
#pragma unroll
    for (int k = 0; k < 16; ++k)
        lds[SZ(base + k * S)] = d[k];
    __syncthreads();
}

// Own-slot pair combine — proven r5/r17-r18.
__device__ inline void combine_pair16(float2* __restrict__ L,
                                      const float2* __restrict__ Kfrow,
                                      int m, bool write_partner) {
    float2 Zq = L[SZ(m & 4095)];
    float2 Zr = L[SZ((4096 - m) & 4095)];
    float sn, cs;
    __sincosf((float)(-3.141592653589793 / 4096.0) * (float)m, &sn, &cs);
    float pr = Zq.x + Zr.x, pi2 = Zq.y - Zr.y;
    float dr = Zq.x - Zr.x, di = Zq.y + Zr.y;
    float jt_r = -sn * dr - cs * di;
    float jt_i =  cs * dr - sn * di;
    float2 Xm  = make_float2(0.5f * (pr - jt_r),  0.5f * ( pi2 - jt_i));
    float2 Xm2 = make_float2(0.5f * (pr + jt_r),  0.5f * (-pi2 - jt_i));
    float2 Ym  = cmul(Xm,  Kfrow[m]);
    float2 Ym2 = cmul(Xm2, Kfrow[4096 - m]);
    float qr = Ym.x + Ym2.x, qi = Ym.y - Ym2.y;
    float er = Ym.x - Ym2.x, ei = Ym.y + Ym2.y;
    float gr2 = sn * er - cs * ei;
    float gi2 = sn * ei + cs * er;
    L[SZ(m & 4095)] = make_float2(0.5f * (qr + gr2), -0.5f * (qi + gi2));
    if (write_partner)
        L[SZ(4096 - m)] = make_float2(0.5f * (qr - gr2), 0.5f * (qi - gi2));
}

// K_hat single bin — proven r2-r18.
__device__ inline float2 khat_bin(int i, int k,
                                  const float* __restrict__ Bm,
                                  const float* __restrict__ Cm,
                                  const float* __restrict__ Lm,
                                  const float* __restrict__ Pm,
                                  const float* __restrict__ Qm) {
    float theta = (float)(6.283185307179586 / (double)SEQ) * (float)k;
    float sn, cs;
    sincosf(theta, &sn, &cs);
    float tr = 1.0f - cs, ti = -sn;
    float br = 1.0f + cs, bi = sn;
    float idn = 1.0f / (br * br + bi * bi);
    float gr = 20.0f * (tr * br + ti * bi) * idn;
    float gi = 20.0f * (ti * br - tr * bi) * idn;
    float cr = 2.0f * br * idn;
    float ci = -2.0f * bi * idn;

    const float* Brow = Bm + i * H_DIM;
    const float* Crow = Cm + i * H_DIM;
    const float* Lrow = Lm + i * H_DIM;
    const float* Prow = Pm + i * H_DIM;
    const float* Qrow = Qm + i * H_DIM;

    float k00r = 0.f, k00i = 0.f, k01r = 0.f, k01i = 0.f;
    float k10r = 0.f, k10i = 0.f, k11r = 0.f, k11i = 0.f;
#pragma unroll 8
    for (int h = 0; h < H_DIM; ++h) {
        float lam = Lrow[h];
        float drr = gr - lam;
        float dii = gi;
        float im = 1.0f / (drr * drr + dii * dii);
        float ivr = drr * im;
        float ivi = -dii * im;
        float bv = Brow[h], cv = Crow[h], pv = Prow[h], qv = Qrow[h];
        float cb = cv * bv;
        float cp = cv * pv;
        float qb = qv * bv;
        float qp = qv * pv;
        k00r += cb * ivr; k00i += cb * ivi;
        k01r += cp * ivr; k01i += cp * ivi;
        k10r += qb * ivr; k10i += qb * ivi;
        k11r += qp * ivr; k11i += qp * ivi;
    }
    float t1r = 1.0f + k11r, t1i = k11i;
    float t2r = k01r * t1r - k01i * t1i;
    float t2i = k01r * t1i + k01i * t1r;
    float t3r = t2r * k10r - t2i * k10i;
    float t3i = t2r * k10i + t2i * k10r;
    float nr = k00r - t3r, ni = k00i - t3i;
    return make_float2(cr * nr - ci * ni, cr * ni + ci * nr);
}

// ===========================================================================
// Kernel 1: tiled transpose x -> xT + khat + even-Kf hoist (r18 verbatim).
// ===========================================================================
__global__ __launch_bounds__(256) void k1_transpose_khat(const float* __restrict__ x,
                                                         const float* __restrict__ Bm,
                                                         const float* __restrict__ Cm,
                                                         const float* __restrict__ Lm,
                                                         const float* __restrict__ Pm,
                                                         const float* __restrict__ Qm) {
    __shared__ float t[64][65];
    const int blk = blockIdx.x;
    const int b = blk >> 7;
    const int rest = blk & 127;
    const int nt = rest >> 1;
    const int it = rest & 1;
    const int tx = threadIdx.x & 63;
    const int ty = threadIdx.x >> 6;
    const int n0 = nt * 64, i0 = it * 64;

    const float* xb = x + (size_t)b * SEQ * I_DIM;
#pragma unroll
    for (int r = 0; r < 16; ++r) {
        int nl = r * 4 + ty;
        t[nl][tx] = xb[(size_t)(n0 + nl) * I_DIM + i0 + tx];
    }
    __syncthreads();
#pragma unroll
    for (int r = 0; r < 16; ++r) {
        int il = r * 4 + ty;
        g_xT[((size_t)b * I_DIM + i0 + il) * SEQ + n0 + tx] = t[tx][il];
    }

    const int ch = blk >> 3, sl = blk & 7;
    const int k = sl * 256 + threadIdx.x;
    float2 hv = khat_bin(ch, k, Bm, Cm, Lm, Pm, Qm);
    g_Hh[(size_t)ch * NBIN + k] = hv;
    g_Kf[(size_t)ch * NBIN2 + 2 * k] = hv;          // even bins: exact
    if (sl == 0 && threadIdx.x == 0) {
        float2 hn = khat_bin(ch, 2048, Bm, Cm, Lm, Pm, Qm);
        g_Hh[(size_t)ch * NBIN + 2048] = hn;
        g_Kf[(size_t)ch * NBIN2 + 4096] = hn;
    }
}

// ===========================================================================
// Kernel 2: kprep-16 odd bins, phase-A/B register fusion (r18 verbatim).
// ===========================================================================
__global__ __launch_bounds__(256) void k2_kprep() {
    __shared__ float2 L[4096];
    const int u = threadIdx.x;
    const int i = blockIdx.x;
    const float2* Hrow = g_Hh + (size_t)i * NBIN;

    {
        float2 d[16];
#pragma unroll
        for (int j = 0; j < 16; ++j) {
            int m = u + (j << 8);
            float2 h;
            if (m <= 2048) h = Hrow[m];
            else { float2 tt = Hrow[4096 - m]; h = make_float2(tt.x, -tt.y); }
            d[j] = make_float2(h.x, -h.y);
        }
        dft16(d);
        s1_twiddle_write(L, u, d);
        __syncthreads();
    }
    stage16<16>(L, u);

    {
        float2 d[16];
#pragma unroll
        for (int j = 0; j < 16; ++j) d[j] = L[SZ(u + (j << 8))];
        __syncthreads();
        dft16(d);

        const float2 W32[16] = {
            make_float2( 1.00000000f,  0.00000000f), make_float2( 0.98078528f, -0.19509032f),
            make_float2( 0.92387953f, -0.38268343f), make_float2( 0.83146961f, -0.55557023f),
            make_float2( 0.70710678f, -0.70710678f), make_float2( 0.55557023f, -0.83146961f),
            make_float2( 0.38268343f, -0.92387953f), make_float2( 0.19509032f, -0.98078528f),
            make_float2( 0.00000000f, -1.00000000f), make_float2(-0.19509032f, -0.98078528f),
            make_float2(-0.38268343f, -0.92387953f), make_float2(-0.55557023f, -0.83146961f),
            make_float2(-0.70710678f, -0.70710678f), make_float2(-0.83146961f, -0.55557023f),
            make_float2(-0.92387953f, -0.38268343f), make_float2(-0.98078528f, -0.19509032f)};
        float snu, csu;
        __sincosf((float)(-3.141592653589793 / 4096.0) * (float)u, &snu, &csu);
        float2 wu = make_float2(csu, snu);
#pragma unroll
        for (int j = 0; j < 16; ++j) {
            float kr = d[j].x * (1.0f / 4096.0f);
            float2 w = cmul(wu, W32[j]);
            d[j] = make_float2(kr * w.x, kr * w.y);
        }
        dft16(d);
        s1_twiddle_write(L, u, d);
        __syncthreads();
    }
    stage16<16>(L, u);

    float2 e[16];
#pragma unroll
    for (int j = 0; j < 16; ++j) e[j] = L[SZ(u + (j << 8))];
    dft16(e);
    float2* Kfrow = g_Kf + (size_t)i * NBIN2;
#pragma unroll
    for (int k = 0; k < 8; ++k)
        Kfrow[2 * (u + (k << 8)) + 1] = e[k];
}

// ===========================================================================
// Kernel 3: fused conv per (b,i) — r17/r18 body, NEW: __launch_bounds__(256,5)
// -> 5 blocks/CU (VGPR cap ~102; 32KB LDS allows 5). The single A/B change.
// ===========================================================================
__global__ __launch_bounds__(256, 5) void k3_fused_conv() {
    __shared__ float2 L[4096];
    const int u = threadIdx.x;
    const int blk = blockIdx.x;          // 0..1023
    const int b = blk & 7;               // batch -> XCD affinity
    const int i = blk >> 3;

    {
        const float2* xrow = (const float2*)(g_xT + ((size_t)b * I_DIM + i) * SEQ);
        float2 xx[8];
#pragma unroll
        for (int j = 0; j < 8; ++j) xx[j] = xrow[u + (j << 8)];
        float2 e[8], o[8], bb[16];
        dft8hz(xx[0], xx[2], xx[4], xx[6], e);
        dft8hz(xx[1], xx[3], xx[5], xx[7], o);
        combine16(e, o, bb);
        s1_twiddle_write(L, u, bb);
        __syncthreads();
    }
    stage16<16>(L, u);
    stage16<256>(L, u);                  // Zx natural order in LDS

    const float2* Kfrow = g_Kf + (size_t)i * NBIN2;
#pragma unroll
    for (int r = 0; r < 8; ++r) {
        int m = u + (r << 8);            // 0..2047
        combine_pair16(L, Kfrow, m, m != 0);
    }
    if (u == 0)
        combine_pair16(L, Kfrow, 2048, false);
    __syncthreads();

    stage16<1>(L, u);
    stage16<16>(L, u);

    float2 f[16];
#pragma unroll
    for (int j = 0; j < 16; ++j) f[j] = L[SZ(u + (j << 8))];
    dft16(f);
    const float inv = 1.0f / 4096.0f;
    float2* yrow = (float2*)(g_Yt + ((size_t)b * I_DIM + i) * SEQ);
#pragma unroll
    for (int k = 0; k < 8; ++k)
        yrow[u + (k << 8)] = make_float2(f[k].x * inv, -f[k].y * inv);
}

// ===========================================================================
// Kernel 4: tiled transpose yT -> y (r13-r18 verbatim — proven).
// ===========================================================================
__global__ __launch_bounds__(256) void k4_transpose_out(float* __restrict__ y) {
    __shared__ float t[64][65];
    const int blk = blockIdx.x;
    const int b = blk >> 7;
    const int rest = blk & 127;
    const int nt = rest >> 1;
    const int it = rest & 1;
    const int tx = threadIdx.x & 63;
    const int ty = threadIdx.x >> 6;
    const int n0 = nt * 64, i0 = it * 64;

#pragma unroll
    for (int r = 0; r < 16; ++r) {
        int il = r * 4 + ty;
        t[il][tx] = g_Yt[((size_t)b * I_DIM + i0 + il) * SEQ + n0 + tx];
    }
    __syncthreads();
    float* yb = y + (size_t)b * SEQ * I_DIM;
#pragma unroll
    for (int r = 0; r < 16; ++r) {
        int nl = r * 4 + ty;
        yb[(size_t)(n0 + nl) * I_DIM + i0 + tx] = t[tx][nl];
    }
}

// ---------------------------------------------------------------------------
extern "C" void kernel_launch(void* const* d_in, const int* in_sizes, int n_in,
                              void* d_out, int out_size, void* d_ws, size_t ws_size,
                              hipStream_t stream) {
    const float* x  = (const float*)d_in[0];
    const float* Bm = (const float*)d_in[1];
    const float* Cm = (const float*)d_in[2];
    const float* Lm = (const float*)d_in[3];
    const float* Pm = (const float*)d_in[4];
    const float* Qm = (const float*)d_in[5];
    float* out = (float*)d_out;

    k1_transpose_khat<<<1024, 256, 0, stream>>>(x, Bm, Cm, Lm, Pm, Qm);
    k2_kprep<<<I_DIM, 256, 0, stream>>>();
    k3_fused_conv<<<BATCH * I_DIM, 256, 0, stream>>>();
    k4_transpose_out<<<1024, 256, 0, stream>>>(out);
}

// Round 20
// 64.227 us; speedup vs baseline: 1.5835x; 1.5835x over previous
//
#include <hip/hip_runtime.h>

#define I_DIM 128
#define H_DIM 64
#define BATCH 8
#define SEQ   4096
#define NBIN  (SEQ/2 + 1)     // 2049
#define NBIN2 (SEQ + 1)       // 4097

// 3-nibble XOR swizzle — proven r13-r18.
#define SZ(a) ((a) ^ (((a) >> 4) & 15) ^ (((a) >> 8) & 15))

// Module-scope device scratch (graph-capture safe, fully rewritten per call).
__device__ float  g_xT[(size_t)BATCH * I_DIM * SEQ];   // 16.8 MB
__device__ float2 g_Hh[I_DIM * NBIN];                  // 2.1 MB
__device__ float2 g_Kf[I_DIM * NBIN2];                 // 4.2 MB
__device__ float  g_Yt[(size_t)BATCH * I_DIM * SEQ];   // 16.8 MB

__device__ inline float2 cmul(float2 a, float2 b) {
    return make_float2(a.x * b.x - a.y * b.y, a.x * b.y + a.y * b.x);
}
__device__ inline float2 cadd(float2 a, float2 b) { return make_float2(a.x + b.x, a.y + b.y); }
__device__ inline float2 csub(float2 a, float2 b) { return make_float2(a.x - b.x, a.y - b.y); }

// DFT8 — proven r4-r18.
__device__ inline void dft8(float2 a[8]) {
    const float C = 0.70710678118654752f;
    float2 s0 = cadd(a[0], a[4]), s1 = cadd(a[1], a[5]);
    float2 s2 = cadd(a[2], a[6]), s3 = cadd(a[3], a[7]);
    float2 d0 = csub(a[0], a[4]), d1 = csub(a[1], a[5]);
    float2 d2 = csub(a[2], a[6]), d3 = csub(a[3], a[7]);
    d1 = make_float2(C * (d1.x + d1.y), C * (d1.y - d1.x));
    d2 = make_float2(d2.y, -d2.x);
    d3 = make_float2(C * (d3.y - d3.x), -C * (d3.x + d3.y));
    {
        float2 p0 = cadd(s0, s2), p1 = cadd(s1, s3);
        float2 m0 = csub(s0, s2), m1 = csub(s1, s3);
        m1 = make_float2(m1.y, -m1.x);
        a[0] = cadd(p0, p1); a[4] = csub(p0, p1);
        a[2] = cadd(m0, m1); a[6] = csub(m0, m1);
    }
    {
        float2 p0 = cadd(d0, d2), p1 = cadd(d1, d3);
        float2 m0 = csub(d0, d2), m1 = csub(d1, d3);
        m1 = make_float2(m1.y, -m1.x);
        a[1] = cadd(p0, p1); a[5] = csub(p0, p1);
        a[3] = cadd(m0, m1); a[7] = csub(m0, m1);
    }
}

// DFT8 of (x0..x3,0,0,0,0) — proven r8-r18.
__device__ inline void dft8hz(float2 x0, float2 x1, float2 x2, float2 x3,
                              float2 b[8]) {
    const float C = 0.70710678118654752f;
    float2 p0 = cadd(x0, x2), p1 = cadd(x1, x3);
    float2 m0 = csub(x0, x2), m1t = csub(x1, x3);
    float2 m1 = make_float2(m1t.y, -m1t.x);
    b[0] = cadd(p0, p1); b[4] = csub(p0, p1);
    b[2] = cadd(m0, m1); b[6] = csub(m0, m1);
    float2 c1 = make_float2(C * (x1.x + x1.y), C * (x1.y - x1.x));
    float2 c2 = make_float2(x2.y, -x2.x);
    float2 c3 = make_float2(C * (x3.y - x3.x), -C * (x3.x + x3.y));
    float2 q0 = cadd(x0, c2), q1 = cadd(c1, c3);
    float2 n0 = csub(x0, c2), n1t = csub(c1, c3);
    float2 n1 = make_float2(n1t.y, -n1t.x);
    b[1] = cadd(q0, q1); b[5] = csub(q0, q1);
    b[3] = cadd(n0, n1); b[7] = csub(n0, n1);
}

// DIT combine — proven r13-r18.
__device__ inline void combine16(const float2 e[8], const float2 o[8],
                                 float2 b[16]) {
    const float C  = 0.70710678118654752f;
    const float C1 = 0.92387953251128674f;
    const float S1 = 0.38268343236508977f;
    float2 t;
    b[0] = cadd(e[0], o[0]);  b[8]  = csub(e[0], o[0]);
    t = cmul(o[1], make_float2( C1, -S1)); b[1] = cadd(e[1], t); b[9]  = csub(e[1], t);
    t = cmul(o[2], make_float2(  C,  -C)); b[2] = cadd(e[2], t); b[10] = csub(e[2], t);
    t = cmul(o[3], make_float2( S1, -C1)); b[3] = cadd(e[3], t); b[11] = csub(e[3], t);
    t = make_float2(o[4].y, -o[4].x);      b[4] = cadd(e[4], t); b[12] = csub(e[4], t);
    t = cmul(o[5], make_float2(-S1, -C1)); b[5] = cadd(e[5], t); b[13] = csub(e[5], t);
    t = cmul(o[6], make_float2( -C,  -C)); b[6] = cadd(e[6], t); b[14] = csub(e[6], t);
    t = cmul(o[7], make_float2(-C1, -S1)); b[7] = cadd(e[7], t); b[15] = csub(e[7], t);
}

// DFT16 — proven r13-r18.
__device__ inline void dft16(float2 a[16]) {
    float2 e[8] = {a[0], a[2], a[4], a[6], a[8], a[10], a[12], a[14]};
    float2 o[8] = {a[1], a[3], a[5], a[7], a[9], a[11], a[13], a[15]};
    dft8(e); dft8(o);
    combine16(e, o, a);
}

// S1-fused twiddle+write — proven r13-r18.
__device__ inline void s1_twiddle_write(float2* __restrict__ lds, int u,
                                        float2 b[16]) {
    float sn, cs;
    __sincosf((float)(-6.283185307179586 / 4096.0) * (float)u, &sn, &cs);
    float2 w1 = make_float2(cs, sn);
    float2 w2 = cmul(w1, w1), w3 = cmul(w2, w1), w4 = cmul(w2, w2);
    float2 w5 = cmul(w3, w2), w6 = cmul(w3, w3), w7 = cmul(w4, w3);
    float2 w8 = cmul(w4, w4);
    const int base = 16 * u;
    lds[SZ(base + 0)]  = b[0];
    lds[SZ(base + 1)]  = cmul(b[1], w1);
    lds[SZ(base + 2)]  = cmul(b[2], w2);
    lds[SZ(base + 3)]  = cmul(b[3], w3);
    lds[SZ(base + 4)]  = cmul(b[4], w4);
    lds[SZ(base + 5)]  = cmul(b[5], w5);
    lds[SZ(base + 6)]  = cmul(b[6], w6);
    lds[SZ(base + 7)]  = cmul(b[7], w7);
    lds[SZ(base + 8)]  = cmul(b[8], w8);
    lds[SZ(base + 9)]  = cmul(cmul(b[9],  w1), w8);
    lds[SZ(base + 10)] = cmul(cmul(b[10], w2), w8);
    lds[SZ(base + 11)] = cmul(cmul(b[11], w3), w8);
    lds[SZ(base + 12)] = cmul(cmul(b[12], w4), w8);
    lds[SZ(base + 13)] = cmul(cmul(b[13], w5), w8);
    lds[SZ(base + 14)] = cmul(cmul(b[14], w6), w8);
    lds[SZ(base + 15)] = cmul(cmul(b[15], w7), w8);
}

// Radix-16 Stockham stage — proven r13-r18.
template <int S>
__device__ inline void stage16(float2* __restrict__ lds, int u) {
    float2 d[16];
#pragma unroll
    for (int j = 0; j < 16; ++j) d[j] = lds[SZ(u + 256 * j)];
    __syncthreads();
    const int q = u & (S - 1);
    dft16(d);
    if constexpr (S < 256) {
        float sn, cs;
        __sincosf((float)(-6.283185307179586 / 4096.0) * (float)(u - q), &sn, &cs);
        float2 w1 = make_float2(cs, sn);
        float2 w2 = cmul(w1, w1), w3 = cmul(w2, w1), w4 = cmul(w2, w2);
        float2 w5 = cmul(w3, w2), w6 = cmul(w3, w3), w7 = cmul(w4, w3);
        float2 w8 = cmul(w4, w4);
        d[1]  = cmul(d[1], w1);  d[2]  = cmul(d[2], w2);
        d[3]  = cmul(d[3], w3);  d[4]  = cmul(d[4], w4);
        d[5]  = cmul(d[5], w5);  d[6]  = cmul(d[6], w6);
        d[7]  = cmul(d[7], w7);  d[8]  = cmul(d[8], w8);
        d[9]  = cmul(cmul(d[9],  w1), w8);
        d[10] = cmul(cmul(d[10], w2), w8);
        d[11] = cmul(cmul(d[11], w3), w8);
        d[12] = cmul(cmul(d[12], w4), w8);
        d[13] = cmul(cmul(d[13], w5), w8);
        d[14] = cmul(cmul(d[14], w6), w8);
        d[15] = cmul(cmul(d[15], w7), w8);
    }
    const int base = 16 * u - 15 * q;
#pragma unroll
    for (int k = 0; k < 16; ++k)
        lds[SZ(base + k * S)] = d[k];
    __syncthreads();
}

// Own-slot pair combine — proven r5/r17-r18.
__device__ inline void combine_pair16(float2* __restrict__ L,
                                      const float2* __restrict__ Kfrow,
                                      int m, bool write_partner) {
    float2 Zq = L[SZ(m & 4095)];
    float2 Zr = L[SZ((4096 - m) & 4095)];
    float sn, cs;
    __sincosf((float)(-3.141592653589793 / 4096.0) * (float)m, &sn, &cs);
    float pr = Zq.x + Zr.x, pi2 = Zq.y - Zr.y;
    float dr = Zq.x - Zr.x, di = Zq.y + Zr.y;
    float jt_r = -sn * dr - cs * di;
    float jt_i =  cs * dr - sn * di;
    float2 Xm  = make_float2(0.5f * (pr - jt_r),  0.5f * ( pi2 - jt_i));
    float2 Xm2 = make_float2(0.5f * (pr + jt_r),  0.5f * (-pi2 - jt_i));
    float2 Ym  = cmul(Xm,  Kfrow[m]);
    float2 Ym2 = cmul(Xm2, Kfrow[4096 - m]);
    float qr = Ym.x + Ym2.x, qi = Ym.y - Ym2.y;
    float er = Ym.x - Ym2.x, ei = Ym.y + Ym2.y;
    float gr2 = sn * er - cs * ei;
    float gi2 = sn * ei + cs * er;
    L[SZ(m & 4095)] = make_float2(0.5f * (qr + gr2), -0.5f * (qi + gi2));
    if (write_partner)
        L[SZ(4096 - m)] = make_float2(0.5f * (qr - gr2), 0.5f * (qi - gi2));
}

// K_hat single bin — proven r2-r18.
__device__ inline float2 khat_bin(int i, int k,
                                  const float* __restrict__ Bm,
                                  const float* __restrict__ Cm,
                                  const float* __restrict__ Lm,
                                  const float* __restrict__ Pm,
                                  const float* __restrict__ Qm) {
    float theta = (float)(6.283185307179586 / (double)SEQ) * (float)k;
    float sn, cs;
    sincosf(theta, &sn, &cs);
    float tr = 1.0f - cs, ti = -sn;
    float br = 1.0f + cs, bi = sn;
    float idn = 1.0f / (br * br + bi * bi);
    float gr = 20.0f * (tr * br + ti * bi) * idn;
    float gi = 20.0f * (ti * br - tr * bi) * idn;
    float cr = 2.0f * br * idn;
    float ci = -2.0f * bi * idn;

    const float* Brow = Bm + i * H_DIM;
    const float* Crow = Cm + i * H_DIM;
    const float* Lrow = Lm + i * H_DIM;
    const float* Prow = Pm + i * H_DIM;
    const float* Qrow = Qm + i * H_DIM;

    float k00r = 0.f, k00i = 0.f, k01r = 0.f, k01i = 0.f;
    float k10r = 0.f, k10i = 0.f, k11r = 0.f, k11i = 0.f;
#pragma unroll 8
    for (int h = 0; h < H_DIM; ++h) {
        float lam = Lrow[h];
        float drr = gr - lam;
        float dii = gi;
        float im = 1.0f / (drr * drr + dii * dii);
        float ivr = drr * im;
        float ivi = -dii * im;
        float bv = Brow[h], cv = Crow[h], pv = Prow[h], qv = Qrow[h];
        float cb = cv * bv;
        float cp = cv * pv;
        float qb = qv * bv;
        float qp = qv * pv;
        k00r += cb * ivr; k00i += cb * ivi;
        k01r += cp * ivr; k01i += cp * ivi;
        k10r += qb * ivr; k10i += qb * ivi;
        k11r += qp * ivr; k11i += qp * ivi;
    }
    float t1r = 1.0f + k11r, t1i = k11i;
    float t2r = k01r * t1r - k01i * t1i;
    float t2i = k01r * t1i + k01i * t1r;
    float t3r = t2r * k10r - t2i * k10i;
    float t3i = t2r * k10i + t2i * k10r;
    float nr = k00r - t3r, ni = k00i - t3i;
    return make_float2(cr * nr - ci * ni, cr * ni + ci * nr);
}

// ===========================================================================
// Kernel A: khat only (1024 blocks, 1 bin/thread) + even-Kf hoist.
// Runs first; transpose does NOT depend on it and moves to kB.
// ===========================================================================
__global__ __launch_bounds__(256) void kA_khat(const float* __restrict__ Bm,
                                               const float* __restrict__ Cm,
                                               const float* __restrict__ Lm,
                                               const float* __restrict__ Pm,
                                               const float* __restrict__ Qm) {
    const int ch = blockIdx.x >> 3, sl = blockIdx.x & 7;
    const int k = sl * 256 + threadIdx.x;
    float2 hv = khat_bin(ch, k, Bm, Cm, Lm, Pm, Qm);
    g_Hh[(size_t)ch * NBIN + k] = hv;
    g_Kf[(size_t)ch * NBIN2 + 2 * k] = hv;          // even bins: exact
    if (sl == 0 && threadIdx.x == 0) {
        float2 hn = khat_bin(ch, 2048, Bm, Cm, Lm, Pm, Qm);
        g_Hh[(size_t)ch * NBIN + 2048] = hn;
        g_Kf[(size_t)ch * NBIN2 + 4096] = hn;
    }
}

// ===========================================================================
// Kernel B: blocks [0,128)   -> kprep-16 odd bins (r18 k2 body, verbatim)
//           blocks [128,1152) -> tiled transpose x -> xT (r18 k1 part)
// The kprep pole overlaps the 1024 transpose blocks (r8/r10 pattern).
// One aliased 32 KB LDS buffer (avoids r12's summed-allocation mistake).
// ===========================================================================
__global__ __launch_bounds__(256) void kB_kprep_transpose(const float* __restrict__ x) {
    __shared__ float2 L[4096];
    const int tid = threadIdx.x;

    if (blockIdx.x < I_DIM) {
        const int u = tid;
        const int i = blockIdx.x;
        const float2* Hrow = g_Hh + (size_t)i * NBIN;

        // phase A: icfft4096 of conj(H_ext), S1 fused from global
        {
            float2 d[16];
#pragma unroll
            for (int j = 0; j < 16; ++j) {
                int m = u + (j << 8);
                float2 h;
                if (m <= 2048) h = Hrow[m];
                else { float2 tt = Hrow[4096 - m]; h = make_float2(tt.x, -tt.y); }
                d[j] = make_float2(h.x, -h.y);
            }
            dft16(d);
            s1_twiddle_write(L, u, d);
            __syncthreads();
        }
        stage16<16>(L, u);

        // FUSED stage16<256> + v-pack + phase-B S1 (r18, register identity)
        {
            float2 d[16];
#pragma unroll
            for (int j = 0; j < 16; ++j) d[j] = L[SZ(u + (j << 8))];
            __syncthreads();
            dft16(d);

            const float2 W32[16] = {
                make_float2( 1.00000000f,  0.00000000f), make_float2( 0.98078528f, -0.19509032f),
                make_float2( 0.92387953f, -0.38268343f), make_float2( 0.83146961f, -0.55557023f),
                make_float2( 0.70710678f, -0.70710678f), make_float2( 0.55557023f, -0.83146961f),
                make_float2( 0.38268343f, -0.92387953f), make_float2( 0.19509032f, -0.98078528f),
                make_float2( 0.00000000f, -1.00000000f), make_float2(-0.19509032f, -0.98078528f),
                make_float2(-0.38268343f, -0.92387953f), make_float2(-0.55557023f, -0.83146961f),
                make_float2(-0.70710678f, -0.70710678f), make_float2(-0.83146961f, -0.55557023f),
                make_float2(-0.92387953f, -0.38268343f), make_float2(-0.98078528f, -0.19509032f)};
            float snu, csu;
            __sincosf((float)(-3.141592653589793 / 4096.0) * (float)u, &snu, &csu);
            float2 wu = make_float2(csu, snu);
#pragma unroll
            for (int j = 0; j < 16; ++j) {
                float kr = d[j].x * (1.0f / 4096.0f);
                float2 w = cmul(wu, W32[j]);
                d[j] = make_float2(kr * w.x, kr * w.y);
            }
            dft16(d);
            s1_twiddle_write(L, u, d);
            __syncthreads();
        }
        stage16<16>(L, u);

        float2 e[16];
#pragma unroll
        for (int j = 0; j < 16; ++j) e[j] = L[SZ(u + (j << 8))];
        dft16(e);
        float2* Kfrow = g_Kf + (size_t)i * NBIN2;
#pragma unroll
        for (int k = 0; k < 8; ++k)
            Kfrow[2 * (u + (k << 8)) + 1] = e[k];
    } else {
        // tiled transpose x[b][n][i] -> xT[b][i][n] (r18 k1 part)
        float (*t)[65] = reinterpret_cast<float(*)[65]>(L);
        const int blk = blockIdx.x - I_DIM;  // 0..1023
        const int b = blk >> 7;
        const int rest = blk & 127;
        const int nt = rest >> 1;
        const int it = rest & 1;
        const int tx = tid & 63;
        const int ty = tid >> 6;
        const int n0 = nt * 64, i0 = it * 64;

        const float* xb = x + (size_t)b * SEQ * I_DIM;
#pragma unroll
        for (int r = 0; r < 16; ++r) {
            int nl = r * 4 + ty;
            t[nl][tx] = xb[(size_t)(n0 + nl) * I_DIM + i0 + tx];
        }
        __syncthreads();
#pragma unroll
        for (int r = 0; r < 16; ++r) {
            int il = r * 4 + ty;
            g_xT[((size_t)b * I_DIM + i0 + il) * SEQ + n0 + tx] = t[tx][il];
        }
    }
}

// ===========================================================================
// Kernel 3: fused conv per (b,i) — r17/r18 body, plain launch bounds
// (r19's (256,5) reverted: VGPR 48 + 178 MB spill traffic).
// ===========================================================================
__global__ __launch_bounds__(256) void k3_fused_conv() {
    __shared__ float2 L[4096];
    const int u = threadIdx.x;
    const int blk = blockIdx.x;          // 0..1023
    const int b = blk & 7;               // batch -> XCD affinity
    const int i = blk >> 3;

    {
        const float2* xrow = (const float2*)(g_xT + ((size_t)b * I_DIM + i) * SEQ);
        float2 xx[8];
#pragma unroll
        for (int j = 0; j < 8; ++j) xx[j] = xrow[u + (j << 8)];
        float2 e[8], o[8], bb[16];
        dft8hz(xx[0], xx[2], xx[4], xx[6], e);
        dft8hz(xx[1], xx[3], xx[5], xx[7], o);
        combine16(e, o, bb);
        s1_twiddle_write(L, u, bb);
        __syncthreads();
    }
    stage16<16>(L, u);
    stage16<256>(L, u);                  // Zx natural order in LDS

    const float2* Kfrow = g_Kf + (size_t)i * NBIN2;
#pragma unroll
    for (int r = 0; r < 8; ++r) {
        int m = u + (r << 8);            // 0..2047
        combine_pair16(L, Kfrow, m, m != 0);
    }
    if (u == 0)
        combine_pair16(L, Kfrow, 2048, false);
    __syncthreads();

    stage16<1>(L, u);
    stage16<16>(L, u);

    float2 f[16];
#pragma unroll
    for (int j = 0; j < 16; ++j) f[j] = L[SZ(u + (j << 8))];
    dft16(f);
    const float inv = 1.0f / 4096.0f;
    float2* yrow = (float2*)(g_Yt + ((size_t)b * I_DIM + i) * SEQ);
#pragma unroll
    for (int k = 0; k < 8; ++k)
        yrow[u + (k << 8)] = make_float2(f[k].x * inv, -f[k].y * inv);
}

// ===========================================================================
// Kernel 4: tiled transpose yT -> y (r13-r18 verbatim — proven).
// ===========================================================================
__global__ __launch_bounds__(256) void k4_transpose_out(float* __restrict__ y) {
    __shared__ float t[64][65];
    const int blk = blockIdx.x;
    const int b = blk >> 7;
    const int rest = blk & 127;
    const int nt = rest >> 1;
    const int it = rest & 1;
    const int tx = threadIdx.x & 63;
    const int ty = threadIdx.x >> 6;
    const int n0 = nt * 64, i0 = it * 64;

#pragma unroll
    for (int r = 0; r < 16; ++r) {
        int il = r * 4 + ty;
        t[il][tx] = g_Yt[((size_t)b * I_DIM + i0 + il) * SEQ + n0 + tx];
    }
    __syncthreads();
    float* yb = y + (size_t)b * SEQ * I_DIM;
#pragma unroll
    for (int r = 0; r < 16; ++r) {
        int nl = r * 4 + ty;
        yb[(size_t)(n0 + nl) * I_DIM + i0 + tx] = t[tx][nl];
    }
}

// ---------------------------------------------------------------------------
extern "C" void kernel_launch(void* const* d_in, const int* in_sizes, int n_in,
                              void* d_out, int out_size, void* d_ws, size_t ws_size,
                              hipStream_t stream) {
    const float* x  = (const float*)d_in[0];
    const float* Bm = (const float*)d_in[1];
    const float* Cm = (const float*)d_in[2];
    const float* Lm = (const float*)d_in[3];
    const float* Pm = (const float*)d_in[4];
    const float* Qm = (const float*)d_in[5];
    float* out = (float*)d_out;

    kA_khat<<<1024, 256, 0, stream>>>(Bm, Cm, Lm, Pm, Qm);
    kB_kprep_transpose<<<I_DIM + 1024, 256, 0, stream>>>(x);
    k3_fused_conv<<<BATCH * I_DIM, 256, 0, stream>>>();
    k4_transpose_out<<<1024, 256, 0, stream>>>(out);
}

// Round 21
// 62.717 us; speedup vs baseline: 1.6217x; 1.0241x over previous
//
#include <hip/hip_runtime.h>

#define I_DIM 128
#define H_DIM 64
#define BATCH 8
#define SEQ   4096
#define NBIN  (SEQ/2 + 1)     // 2049
#define NBIN2 (SEQ + 1)       // 4097

// 3-nibble XOR swizzle — proven r13-r20.
#define SZ(a) ((a) ^ (((a) >> 4) & 15) ^ (((a) >> 8) & 15))

// Module-scope device scratch (graph-capture safe, fully rewritten per call).
__device__ float  g_xT[(size_t)BATCH * I_DIM * SEQ];   // 16.8 MB
__device__ float2 g_Hh[I_DIM * NBIN];                  // 2.1 MB
__device__ float2 g_Kf[I_DIM * NBIN2];                 // 4.2 MB
__device__ float  g_Yt[(size_t)BATCH * I_DIM * SEQ];   // 16.8 MB

__device__ inline float2 cmul(float2 a, float2 b) {
    return make_float2(a.x * b.x - a.y * b.y, a.x * b.y + a.y * b.x);
}
__device__ inline float2 cadd(float2 a, float2 b) { return make_float2(a.x + b.x, a.y + b.y); }
__device__ inline float2 csub(float2 a, float2 b) { return make_float2(a.x - b.x, a.y - b.y); }

// DFT8 — proven r4-r20.
__device__ inline void dft8(float2 a[8]) {
    const float C = 0.70710678118654752f;
    float2 s0 = cadd(a[0], a[4]), s1 = cadd(a[1], a[5]);
    float2 s2 = cadd(a[2], a[6]), s3 = cadd(a[3], a[7]);
    float2 d0 = csub(a[0], a[4]), d1 = csub(a[1], a[5]);
    float2 d2 = csub(a[2], a[6]), d3 = csub(a[3], a[7]);
    d1 = make_float2(C * (d1.x + d1.y), C * (d1.y - d1.x));
    d2 = make_float2(d2.y, -d2.x);
    d3 = make_float2(C * (d3.y - d3.x), -C * (d3.x + d3.y));
    {
        float2 p0 = cadd(s0, s2), p1 = cadd(s1, s3);
        float2 m0 = csub(s0, s2), m1 = csub(s1, s3);
        m1 = make_float2(m1.y, -m1.x);
        a[0] = cadd(p0, p1); a[4] = csub(p0, p1);
        a[2] = cadd(m0, m1); a[6] = csub(m0, m1);
    }
    {
        float2 p0 = cadd(d0, d2), p1 = cadd(d1, d3);
        float2 m0 = csub(d0, d2), m1 = csub(d1, d3);
        m1 = make_float2(m1.y, -m1.x);
        a[1] = cadd(p0, p1); a[5] = csub(p0, p1);
        a[3] = cadd(m0, m1); a[7] = csub(m0, m1);
    }
}

// DFT8 of (x0..x3,0,0,0,0) — proven r8-r20.
__device__ inline void dft8hz(float2 x0, float2 x1, float2 x2, float2 x3,
                              float2 b[8]) {
    const float C = 0.70710678118654752f;
    float2 p0 = cadd(x0, x2), p1 = cadd(x1, x3);
    float2 m0 = csub(x0, x2), m1t = csub(x1, x3);
    float2 m1 = make_float2(m1t.y, -m1t.x);
    b[0] = cadd(p0, p1); b[4] = csub(p0, p1);
    b[2] = cadd(m0, m1); b[6] = csub(m0, m1);
    float2 c1 = make_float2(C * (x1.x + x1.y), C * (x1.y - x1.x));
    float2 c2 = make_float2(x2.y, -x2.x);
    float2 c3 = make_float2(C * (x3.y - x3.x), -C * (x3.x + x3.y));
    float2 q0 = cadd(x0, c2), q1 = cadd(c1, c3);
    float2 n0 = csub(x0, c2), n1t = csub(c1, c3);
    float2 n1 = make_float2(n1t.y, -n1t.x);
    b[1] = cadd(q0, q1); b[5] = csub(q0, q1);
    b[3] = cadd(n0, n1); b[7] = csub(n0, n1);
}

// DIT combine — proven r13-r20.
__device__ inline void combine16(const float2 e[8], const float2 o[8],
                                 float2 b[16]) {
    const float C  = 0.70710678118654752f;
    const float C1 = 0.92387953251128674f;
    const float S1 = 0.38268343236508977f;
    float2 t;
    b[0] = cadd(e[0], o[0]);  b[8]  = csub(e[0], o[0]);
    t = cmul(o[1], make_float2( C1, -S1)); b[1] = cadd(e[1], t); b[9]  = csub(e[1], t);
    t = cmul(o[2], make_float2(  C,  -C)); b[2] = cadd(e[2], t); b[10] = csub(e[2], t);
    t = cmul(o[3], make_float2( S1, -C1)); b[3] = cadd(e[3], t); b[11] = csub(e[3], t);
    t = make_float2(o[4].y, -o[4].x);      b[4] = cadd(e[4], t); b[12] = csub(e[4], t);
    t = cmul(o[5], make_float2(-S1, -C1)); b[5] = cadd(e[5], t); b[13] = csub(e[5], t);
    t = cmul(o[6], make_float2( -C,  -C)); b[6] = cadd(e[6], t); b[14] = csub(e[6], t);
    t = cmul(o[7], make_float2(-C1, -S1)); b[7] = cadd(e[7], t); b[15] = csub(e[7], t);
}

// DFT16 — proven r13-r20.
__device__ inline void dft16(float2 a[16]) {
    float2 e[8] = {a[0], a[2], a[4], a[6], a[8], a[10], a[12], a[14]};
    float2 o[8] = {a[1], a[3], a[5], a[7], a[9], a[11], a[13], a[15]};
    dft8(e); dft8(o);
    combine16(e, o, a);
}

// S1-fused twiddle+write — proven r13-r20.
__device__ inline void s1_twiddle_write(float2* __restrict__ lds, int u,
                                        float2 b[16]) {
    float sn, cs;
    __sincosf((float)(-6.283185307179586 / 4096.0) * (float)u, &sn, &cs);
    float2 w1 = make_float2(cs, sn);
    float2 w2 = cmul(w1, w1), w3 = cmul(w2, w1), w4 = cmul(w2, w2);
    float2 w5 = cmul(w3, w2), w6 = cmul(w3, w3), w7 = cmul(w4, w3);
    float2 w8 = cmul(w4, w4);
    const int base = 16 * u;
    lds[SZ(base + 0)]  = b[0];
    lds[SZ(base + 1)]  = cmul(b[1], w1);
    lds[SZ(base + 2)]  = cmul(b[2], w2);
    lds[SZ(base + 3)]  = cmul(b[3], w3);
    lds[SZ(base + 4)]  = cmul(b[4], w4);
    lds[SZ(base + 5)]  = cmul(b[5], w5);
    lds[SZ(base + 6)]  = cmul(b[6], w6);
    lds[SZ(base + 7)]  = cmul(b[7], w7);
    lds[SZ(base + 8)]  = cmul(b[8], w8);
    lds[SZ(base + 9)]  = cmul(cmul(b[9],  w1), w8);
    lds[SZ(base + 10)] = cmul(cmul(b[10], w2), w8);
    lds[SZ(base + 11)] = cmul(cmul(b[11], w3), w8);
    lds[SZ(base + 12)] = cmul(cmul(b[12], w4), w8);
    lds[SZ(base + 13)] = cmul(cmul(b[13], w5), w8);
    lds[SZ(base + 14)] = cmul(cmul(b[14], w6), w8);
    lds[SZ(base + 15)] = cmul(cmul(b[15], w7), w8);
}

// Radix-16 Stockham stage — proven r13-r20.
template <int S>
__device__ inline void stage16(float2* __restrict__ lds, int u) {
    float2 d[16];
#pragma unroll
    for (int j = 0; j < 16; ++j) d[j] = lds[SZ(u + 256 * j)];
    __syncthreads();
    const int q = u & (S - 1);
    dft16(d);
    if constexpr (S < 256) {
        float sn, cs;
        __sincosf((float)(-6.283185307179586 / 4096.0) * (float)(u - q), &sn, &cs);
        float2 w1 = make_float2(cs, sn);
        float2 w2 = cmul(w1, w1), w3 = cmul(w2, w1), w4 = cmul(w2, w2);
        float2 w5 = cmul(w3, w2), w6 = cmul(w3, w3), w7 = cmul(w4, w3);
        float2 w8 = cmul(w4, w4);
        d[1]  = cmul(d[1], w1);  d[2]  = cmul(d[2], w2);
        d[3]  = cmul(d[3], w3);  d[4]  = cmul(d[4], w4);
        d[5]  = cmul(d[5], w5);  d[6]  = cmul(d[6], w6);
        d[7]  = cmul(d[7], w7);  d[8]  = cmul(d[8], w8);
        d[9]  = cmul(cmul(d[9],  w1), w8);
        d[10] = cmul(cmul(d[10], w2), w8);
        d[11] = cmul(cmul(d[11], w3), w8);
        d[12] = cmul(cmul(d[12], w4), w8);
        d[13] = cmul(cmul(d[13], w5), w8);
        d[14] = cmul(cmul(d[14], w6), w8);
        d[15] = cmul(cmul(d[15], w7), w8);
    }
    const int base = 16 * u - 15 * q;
#pragma unroll
    for (int k = 0; k < 16; ++k)
        lds[SZ(base + k * S)] = d[k];
    __syncthreads();
}

// Own-slot pair combine — proven r5/r17-r20.
__device__ inline void combine_pair16(float2* __restrict__ L,
                                      const float2* __restrict__ Kfrow,
                                      int m, bool write_partner) {
    float2 Zq = L[SZ(m & 4095)];
    float2 Zr = L[SZ((4096 - m) & 4095)];
    float sn, cs;
    __sincosf((float)(-3.141592653589793 / 4096.0) * (float)m, &sn, &cs);
    float pr = Zq.x + Zr.x, pi2 = Zq.y - Zr.y;
    float dr = Zq.x - Zr.x, di = Zq.y + Zr.y;
    float jt_r = -sn * dr - cs * di;
    float jt_i =  cs * dr - sn * di;
    float2 Xm  = make_float2(0.5f * (pr - jt_r),  0.5f * ( pi2 - jt_i));
    float2 Xm2 = make_float2(0.5f * (pr + jt_r),  0.5f * (-pi2 - jt_i));
    float2 Ym  = cmul(Xm,  Kfrow[m]);
    float2 Ym2 = cmul(Xm2, Kfrow[4096 - m]);
    float qr = Ym.x + Ym2.x, qi = Ym.y - Ym2.y;
    float er = Ym.x - Ym2.x, ei = Ym.y + Ym2.y;
    float gr2 = sn * er - cs * ei;
    float gi2 = sn * ei + cs * er;
    L[SZ(m & 4095)] = make_float2(0.5f * (qr + gr2), -0.5f * (qi + gi2));
    if (write_partner)
        L[SZ(4096 - m)] = make_float2(0.5f * (qr - gr2), 0.5f * (qi - gi2));
}

// K_hat single bin — proven r2-r20.
__device__ inline float2 khat_bin(int i, int k,
                                  const float* __restrict__ Bm,
                                  const float* __restrict__ Cm,
                                  const float* __restrict__ Lm,
                                  const float* __restrict__ Pm,
                                  const float* __restrict__ Qm) {
    float theta = (float)(6.283185307179586 / (double)SEQ) * (float)k;
    float sn, cs;
    sincosf(theta, &sn, &cs);
    float tr = 1.0f - cs, ti = -sn;
    float br = 1.0f + cs, bi = sn;
    float idn = 1.0f / (br * br + bi * bi);
    float gr = 20.0f * (tr * br + ti * bi) * idn;
    float gi = 20.0f * (ti * br - tr * bi) * idn;
    float cr = 2.0f * br * idn;
    float ci = -2.0f * bi * idn;

    const float* Brow = Bm + i * H_DIM;
    const float* Crow = Cm + i * H_DIM;
    const float* Lrow = Lm + i * H_DIM;
    const float* Prow = Pm + i * H_DIM;
    const float* Qrow = Qm + i * H_DIM;

    float k00r = 0.f, k00i = 0.f, k01r = 0.f, k01i = 0.f;
    float k10r = 0.f, k10i = 0.f, k11r = 0.f, k11i = 0.f;
#pragma unroll 8
    for (int h = 0; h < H_DIM; ++h) {
        float lam = Lrow[h];
        float drr = gr - lam;
        float dii = gi;
        float im = 1.0f / (drr * drr + dii * dii);
        float ivr = drr * im;
        float ivi = -dii * im;
        float bv = Brow[h], cv = Crow[h], pv = Prow[h], qv = Qrow[h];
        float cb = cv * bv;
        float cp = cv * pv;
        float qb = qv * bv;
        float qp = qv * pv;
        k00r += cb * ivr; k00i += cb * ivi;
        k01r += cp * ivr; k01i += cp * ivi;
        k10r += qb * ivr; k10i += qb * ivi;
        k11r += qp * ivr; k11i += qp * ivi;
    }
    float t1r = 1.0f + k11r, t1i = k11i;
    float t2r = k01r * t1r - k01i * t1i;
    float t2i = k01r * t1i + k01i * t1r;
    float t3r = t2r * k10r - t2i * k10i;
    float t3i = t2r * k10i + t2i * k10r;
    float nr = k00r - t3r, ni = k00i - t3i;
    return make_float2(cr * nr - ci * ni, cr * ni + ci * nr);
}

// ===========================================================================
// Kernel A: khat only (1024 blocks, 1 bin/thread) + even-Kf hoist (r20).
// ===========================================================================
__global__ __launch_bounds__(256) void kA_khat(const float* __restrict__ Bm,
                                               const float* __restrict__ Cm,
                                               const float* __restrict__ Lm,
                                               const float* __restrict__ Pm,
                                               const float* __restrict__ Qm) {
    const int ch = blockIdx.x >> 3, sl = blockIdx.x & 7;
    const int k = sl * 256 + threadIdx.x;
    float2 hv = khat_bin(ch, k, Bm, Cm, Lm, Pm, Qm);
    g_Hh[(size_t)ch * NBIN + k] = hv;
    g_Kf[(size_t)ch * NBIN2 + 2 * k] = hv;          // even bins: exact
    if (sl == 0 && threadIdx.x == 0) {
        float2 hn = khat_bin(ch, 2048, Bm, Cm, Lm, Pm, Qm);
        g_Hh[(size_t)ch * NBIN + 2048] = hn;
        g_Kf[(size_t)ch * NBIN2 + 4096] = hn;
    }
}

// ===========================================================================
// Kernel B: blocks [0,128) -> kprep-16 odd bins; blocks [128,1152) ->
// tiled transpose x -> xT (r20 verbatim).
// ===========================================================================
__global__ __launch_bounds__(256) void kB_kprep_transpose(const float* __restrict__ x) {
    __shared__ float2 L[4096];
    const int tid = threadIdx.x;

    if (blockIdx.x < I_DIM) {
        const int u = tid;
        const int i = blockIdx.x;
        const float2* Hrow = g_Hh + (size_t)i * NBIN;

        {
            float2 d[16];
#pragma unroll
            for (int j = 0; j < 16; ++j) {
                int m = u + (j << 8);
                float2 h;
                if (m <= 2048) h = Hrow[m];
                else { float2 tt = Hrow[4096 - m]; h = make_float2(tt.x, -tt.y); }
                d[j] = make_float2(h.x, -h.y);
            }
            dft16(d);
            s1_twiddle_write(L, u, d);
            __syncthreads();
        }
        stage16<16>(L, u);

        {
            float2 d[16];
#pragma unroll
            for (int j = 0; j < 16; ++j) d[j] = L[SZ(u + (j << 8))];
            __syncthreads();
            dft16(d);

            const float2 W32[16] = {
                make_float2( 1.00000000f,  0.00000000f), make_float2( 0.98078528f, -0.19509032f),
                make_float2( 0.92387953f, -0.38268343f), make_float2( 0.83146961f, -0.55557023f),
                make_float2( 0.70710678f, -0.70710678f), make_float2( 0.55557023f, -0.83146961f),
                make_float2( 0.38268343f, -0.92387953f), make_float2( 0.19509032f, -0.98078528f),
                make_float2( 0.00000000f, -1.00000000f), make_float2(-0.19509032f, -0.98078528f),
                make_float2(-0.38268343f, -0.92387953f), make_float2(-0.55557023f, -0.83146961f),
                make_float2(-0.70710678f, -0.70710678f), make_float2(-0.83146961f, -0.55557023f),
                make_float2(-0.92387953f, -0.38268343f), make_float2(-0.98078528f, -0.19509032f)};
            float snu, csu;
            __sincosf((float)(-3.141592653589793 / 4096.0) * (float)u, &snu, &csu);
            float2 wu = make_float2(csu, snu);
#pragma unroll
            for (int j = 0; j < 16; ++j) {
                float kr = d[j].x * (1.0f / 4096.0f);
                float2 w = cmul(wu, W32[j]);
                d[j] = make_float2(kr * w.x, kr * w.y);
            }
            dft16(d);
            s1_twiddle_write(L, u, d);
            __syncthreads();
        }
        stage16<16>(L, u);

        float2 e[16];
#pragma unroll
        for (int j = 0; j < 16; ++j) e[j] = L[SZ(u + (j << 8))];
        dft16(e);
        float2* Kfrow = g_Kf + (size_t)i * NBIN2;
#pragma unroll
        for (int k = 0; k < 8; ++k)
            Kfrow[2 * (u + (k << 8)) + 1] = e[k];
    } else {
        float (*t)[65] = reinterpret_cast<float(*)[65]>(L);
        const int blk = blockIdx.x - I_DIM;  // 0..1023
        const int b = blk >> 7;
        const int rest = blk & 127;
        const int nt = rest >> 1;
        const int it = rest & 1;
        const int tx = tid & 63;
        const int ty = tid >> 6;
        const int n0 = nt * 64, i0 = it * 64;

        const float* xb = x + (size_t)b * SEQ * I_DIM;
#pragma unroll
        for (int r = 0; r < 16; ++r) {
            int nl = r * 4 + ty;
            t[nl][tx] = xb[(size_t)(n0 + nl) * I_DIM + i0 + tx];
        }
        __syncthreads();
#pragma unroll
        for (int r = 0; r < 16; ++r) {
            int il = r * 4 + ty;
            g_xT[((size_t)b * I_DIM + i0 + il) * SEQ + n0 + tx] = t[tx][il];
        }
    }
}

// ===========================================================================
// Kernel 3: fused conv per (b,i) — r17-r20 body. SINGLE CHANGE: block->(b,i)
// mapping is now b = blk>>7, i = blk&127, so the 8 batch-blocks sharing Kf
// row i have blk%8 == i%8 -> SAME XCD -> Kf row L2-resident after first
// fetch (T1 mechanism: swizzle for shared-operand blocks; xT rows are
// block-exclusive so the old b-affinity protected nothing).
// ===========================================================================
__global__ __launch_bounds__(256) void k3_fused_conv() {
    __shared__ float2 L[4096];
    const int u = threadIdx.x;
    const int blk = blockIdx.x;          // 0..1023
    const int b = blk >> 7;              // 0..7   (was blk & 7)
    const int i = blk & 127;             // 0..127 (was blk >> 3)

    {
        const float2* xrow = (const float2*)(g_xT + ((size_t)b * I_DIM + i) * SEQ);
        float2 xx[8];
#pragma unroll
        for (int j = 0; j < 8; ++j) xx[j] = xrow[u + (j << 8)];
        float2 e[8], o[8], bb[16];
        dft8hz(xx[0], xx[2], xx[4], xx[6], e);
        dft8hz(xx[1], xx[3], xx[5], xx[7], o);
        combine16(e, o, bb);
        s1_twiddle_write(L, u, bb);
        __syncthreads();
    }
    stage16<16>(L, u);
    stage16<256>(L, u);                  // Zx natural order in LDS

    const float2* Kfrow = g_Kf + (size_t)i * NBIN2;
#pragma unroll
    for (int r = 0; r < 8; ++r) {
        int m = u + (r << 8);            // 0..2047
        combine_pair16(L, Kfrow, m, m != 0);
    }
    if (u == 0)
        combine_pair16(L, Kfrow, 2048, false);
    __syncthreads();

    stage16<1>(L, u);
    stage16<16>(L, u);

    float2 f[16];
#pragma unroll
    for (int j = 0; j < 16; ++j) f[j] = L[SZ(u + (j << 8))];
    dft16(f);
    const float inv = 1.0f / 4096.0f;
    float2* yrow = (float2*)(g_Yt + ((size_t)b * I_DIM + i) * SEQ);
#pragma unroll
    for (int k = 0; k < 8; ++k)
        yrow[u + (k << 8)] = make_float2(f[k].x * inv, -f[k].y * inv);
}

// ===========================================================================
// Kernel 4: tiled transpose yT -> y (r13-r20 verbatim — proven).
// ===========================================================================
__global__ __launch_bounds__(256) void k4_transpose_out(float* __restrict__ y) {
    __shared__ float t[64][65];
    const int blk = blockIdx.x;
    const int b = blk >> 7;
    const int rest = blk & 127;
    const int nt = rest >> 1;
    const int it = rest & 1;
    const int tx = threadIdx.x & 63;
    const int ty = threadIdx.x >> 6;
    const int n0 = nt * 64, i0 = it * 64;

#pragma unroll
    for (int r = 0; r < 16; ++r) {
        int il = r * 4 + ty;
        t[il][tx] = g_Yt[((size_t)b * I_DIM + i0 + il) * SEQ + n0 + tx];
    }
    __syncthreads();
    float* yb = y + (size_t)b * SEQ * I_DIM;
#pragma unroll
    for (int r = 0; r < 16; ++r) {
        int nl = r * 4 + ty;
        yb[(size_t)(n0 + nl) * I_DIM + i0 + tx] = t[tx][nl];
    }
}

// ---------------------------------------------------------------------------
extern "C" void kernel_launch(void* const* d_in, const int* in_sizes, int n_in,
                              void* d_out, int out_size, void* d_ws, size_t ws_size,
                              hipStream_t stream) {
    const float* x  = (const float*)d_in[0];
    const float* Bm = (const float*)d_in[1];
    const float* Cm = (const float*)d_in[2];
    const float* Lm = (const float*)d_in[3];
    const float* Pm = (const float*)d_in[4];
    const float* Qm = (const float*)d_in[5];
    float* out = (float*)d_out;

    kA_khat<<<1024, 256, 0, stream>>>(Bm, Cm, Lm, Pm, Qm);
    kB_kprep_transpose<<<I_DIM + 1024, 256, 0, stream>>>(x);
    k3_fused_conv<<<BATCH * I_DIM, 256, 0, stream>>>();
    k4_transpose_out<<<1024, 256, 0, stream>>>(out);
}